// Round 10
// baseline (493.582 us; speedup 1.0000x reference)
//
#include <hip/hip_runtime.h>
#include <hip/hip_bf16.h>
#include <math.h>

#define B_SZ   2
#define LIN    21760
#define C_DIM  256
#define M_H    8
#define D_H    32
#define NLEV   4
#define NPTS   4
#define FFN    1024
#define NTOK   (B_SZ * LIN)      // 43520
#define NTILE  (NTOK / 32)       // 1360
#define NCONV  (NTOK * C_DIM / 4 / 256)  // 10880
#define LN_EPS 1e-5f

typedef __bf16 bf16;
typedef bf16  bf16x4 __attribute__((ext_vector_type(4)));
typedef bf16  bf16x8 __attribute__((ext_vector_type(8)));
typedef float f32x4  __attribute__((ext_vector_type(4)));

__device__ __constant__ int c_Ht[4] = {128, 64, 32, 16};
__device__ __constant__ int c_Wt[4] = {128, 64, 32, 16};
__device__ __constant__ int c_St[4] = {0, 16384, 20480, 21504};

static __device__ __forceinline__ float bf2f(unsigned short u) {
    union { float f; unsigned int i; } c;
    c.i = ((unsigned int)u) << 16;
    return c.f;
}

// ---------------------------------------------------------------------------
// Prep (merged): blockIdx < NCONV: srcb=bf16(src), qb=bf16(src+pos);
// else: one 32x32 transpose tile of one of the six weight matrices.
// ---------------------------------------------------------------------------
__global__ __launch_bounds__(256) void k_prep(const float* __restrict__ src,
                                              const float* __restrict__ pos,
                                              bf16* __restrict__ srcb,
                                              bf16* __restrict__ qb,
                                              const float* __restrict__ Wv,
                                              const float* __restrict__ Wo,
                                              const float* __restrict__ Wa,
                                              const float* __restrict__ Wout,
                                              const float* __restrict__ W1,
                                              const float* __restrict__ W2,
                                              bf16* __restrict__ Wvt,
                                              bf16* __restrict__ Wqt,
                                              bf16* __restrict__ Woutt,
                                              bf16* __restrict__ W1t,
                                              bf16* __restrict__ W2t) {
    __shared__ float tile[32][33];
    const int bid = blockIdx.x;
    if (bid < NCONV) {
        const int i = bid * 256 + threadIdx.x;
        const float4 s4 = ((const float4*)src)[i];
        const float4 p4 = ((const float4*)pos)[i];
        bf16x4 sb, qb4;
        sb.x = (bf16)s4.x; sb.y = (bf16)s4.y; sb.z = (bf16)s4.z; sb.w = (bf16)s4.w;
        qb4.x = (bf16)(s4.x + p4.x); qb4.y = (bf16)(s4.y + p4.y);
        qb4.z = (bf16)(s4.z + p4.z); qb4.w = (bf16)(s4.w + p4.w);
        ((bf16x4*)srcb)[i] = sb;
        ((bf16x4*)qb)[i]   = qb4;
        return;
    }
    int b = bid - NCONV;
    const float* W; bf16* Wt; int K, N, ntn;
    if      (b < 64)  { W = Wv;   Wt = Wvt;           K = 256;  N = 256;  ntn = 8;            }
    else if (b < 128) { W = Wo;   Wt = Wqt;           K = 256;  N = 256;  ntn = 8;  b -= 64;  }
    else if (b < 160) { W = Wa;   Wt = Wqt + 65536;   K = 256;  N = 128;  ntn = 4;  b -= 128; }
    else if (b < 224) { W = Wout; Wt = Woutt;         K = 256;  N = 256;  ntn = 8;  b -= 160; }
    else if (b < 480) { W = W1;   Wt = W1t;           K = 256;  N = 1024; ntn = 32; b -= 224; }
    else              { W = W2;   Wt = W2t;           K = 1024; N = 256;  ntn = 8;  b -= 480; }

    const int bx = b % ntn;
    const int by = b / ntn;
    const int tx = threadIdx.x & 31, ty = threadIdx.x >> 5;
    const int n0 = bx * 32, k0 = by * 32;
#pragma unroll
    for (int i = 0; i < 32; i += 8)
        tile[ty + i][tx] = W[(long)(k0 + ty + i) * N + n0 + tx];
    __syncthreads();
#pragma unroll
    for (int i = 0; i < 32; i += 8)
        Wt[(long)(n0 + ty + i) * K + k0 + tx] = (bf16)tile[tx][ty + i];
}

// ---------------------------------------------------------------------------
// Shared GEMM prolog: 32-token tile, K=256, A staged+swizzled in LDS.
// (byte-identical math to round 8; BID parameterized for merged dispatch)
// ---------------------------------------------------------------------------
#define GEMM_PROLOG(Aptr, BID)                                                \
    const int t = threadIdx.x;                                                \
    const int lane = t & 63, w = t >> 6;                                      \
    const int c0 = lane & 15, kg = lane >> 4;                                 \
    const long tok0 = (long)(BID) * 32;                                       \
    {                                                                         \
        const bf16x8* src8 = (const bf16x8*)((Aptr) + tok0 * C_DIM);          \
        bf16x8* dst8 = (bf16x8*)xs;                                           \
        for (int i = t; i < 1024; i += 256)                                   \
            dst8[i ^ ((i >> 5) & 7)] = src8[i];                               \
    }                                                                         \
    __syncthreads();                                                          \
    bf16x8 afr[2][8];                                                         \
    _Pragma("unroll")                                                         \
    for (int mh = 0; mh < 2; ++mh) {                                          \
        const int m = mh * 16 + c0;                                           \
        _Pragma("unroll")                                                     \
        for (int kc = 0; kc < 8; ++kc) {                                      \
            const int chunk = m * 32 + kc * 4 + kg;                           \
            afr[mh][kc] = ((const bf16x8*)xs)[chunk ^ (m & 7)];               \
        }                                                                     \
    }

// ---------------------------------------------------------------------------
// K1+K2 merged: blocks [0,NTILE) -> value GEMM; [NTILE,2*NTILE) -> qloc GEMM.
// Bodies byte-identical to round 8's k_value_mfma / k_qloc_mfma.
// ---------------------------------------------------------------------------
__global__ __launch_bounds__(256) void k_vq(const bf16* __restrict__ srcb,
                                            const bf16* __restrict__ qbuf,
                                            const bf16* __restrict__ Wvt,
                                            const float* __restrict__ bv,
                                            bf16* __restrict__ value,
                                            const bf16* __restrict__ Wqt,
                                            const float* __restrict__ bo,
                                            const float* __restrict__ ba,
                                            const float* __restrict__ refp,
                                            float* __restrict__ loc,
                                            float* __restrict__ att) {
    __shared__ bf16 xs[32 * 256];
    if (blockIdx.x < NTILE) {
        GEMM_PROLOG(srcb, blockIdx.x)

        const int b = (int)(tok0 / LIN);
        const int qbase = (int)(tok0 - (long)b * LIN);

#pragma unroll
        for (int nt = 0; nt < 4; ++nt) {
            const int n = w * 64 + nt * 16 + c0;
            f32x4 a0 = {0.f, 0.f, 0.f, 0.f};
            f32x4 a1 = {0.f, 0.f, 0.f, 0.f};
            const bf16* wrow = Wvt + (long)n * 256 + kg * 8;
#pragma unroll
            for (int kc = 0; kc < 8; ++kc) {
                const bf16x8 bfr = *(const bf16x8*)(wrow + kc * 32);
                a0 = __builtin_amdgcn_mfma_f32_16x16x32_bf16(afr[0][kc], bfr, a0, 0, 0, 0);
                a1 = __builtin_amdgcn_mfma_f32_16x16x32_bf16(afr[1][kc], bfr, a1, 0, 0, 0);
            }
            const float bb = bv[n];
            const int m = n >> 5, d = n & 31;
            bf16* vb = value + ((long)(b * M_H + m) * LIN) * D_H + d;
#pragma unroll
            for (int r = 0; r < 4; ++r) {
                const int q0 = qbase + kg * 4 + r;
                vb[(long)q0 * D_H]        = (bf16)(a0[r] + bb);
                vb[(long)(q0 + 16) * D_H] = (bf16)(a1[r] + bb);
            }
        }
    } else {
        GEMM_PROLOG(qbuf, blockIdx.x - NTILE)

#pragma unroll
        for (int nt = 0; nt < 6; ++nt) {
            const int n = w * 96 + nt * 16 + c0;
            f32x4 a0 = {0.f, 0.f, 0.f, 0.f};
            f32x4 a1 = {0.f, 0.f, 0.f, 0.f};
            const bf16* wrow = Wqt + (long)n * 256 + kg * 8;
#pragma unroll
            for (int kc = 0; kc < 8; ++kc) {
                const bf16x8 bfr = *(const bf16x8*)(wrow + kc * 32);
                a0 = __builtin_amdgcn_mfma_f32_16x16x32_bf16(afr[0][kc], bfr, a0, 0, 0, 0);
                a1 = __builtin_amdgcn_mfma_f32_16x16x32_bf16(afr[1][kc], bfr, a1, 0, 0, 0);
            }
            if (n < 256) {
                const int l = (n >> 3) & 3;
                const int c = n & 1;
                const float rnorm = 1.f / ((c == 0) ? (float)c_Wt[l] : (float)c_Ht[l]);
                const float bb = bo[n];
#pragma unroll
                for (int r = 0; r < 4; ++r) {
                    const long t0 = tok0 + kg * 4 + r;
                    const long t1 = t0 + 16;
                    loc[t0 * C_DIM + n] = refp[t0 * 8 + l * 2 + c] + (a0[r] + bb) * rnorm;
                    loc[t1 * C_DIM + n] = refp[t1 * 8 + l * 2 + c] + (a1[r] + bb) * rnorm;
                }
            } else {
                const int j = n - 256;
                const float bb = ba[j];
#pragma unroll
                for (int r = 0; r < 4; ++r) {
                    const long t0 = tok0 + kg * 4 + r;
                    att[t0 * 128 + j]        = a0[r] + bb;
                    att[(t0 + 16) * 128 + j] = a1[r] + bb;
                }
            }
        }
    }
}

// ---------------------------------------------------------------------------
// K3: deformable sampling, two-phase (byte-identical to round 8)
// ---------------------------------------------------------------------------
__global__ __launch_bounds__(256) void k_samp(const unsigned short* __restrict__ value,
                                              const float* __restrict__ loc,
                                              const float* __restrict__ att,
                                              bf16* __restrict__ outb) {
    __shared__ int4   soff[128];
    __shared__ float4 swgt[128];
    const int t = threadIdx.x;
    const long tok = blockIdx.x;

    if (t < 128) {
        const float lg = att[tok * 128 + t];
        float mx = lg;
#pragma unroll
        for (int s = 1; s < 16; s <<= 1) mx = fmaxf(mx, __shfl_xor(mx, s));
        const float e = expf(lg - mx);
        float sm = e;
#pragma unroll
        for (int s = 1; s < 16; s <<= 1) sm += __shfl_xor(sm, s);
        const float a = e / sm;

        const float2 xy = ((const float2*)loc)[tok * 128 + t];
        const int l = (t >> 2) & 3;
        const int H = c_Ht[l], W = c_Wt[l], s0 = c_St[l];
        const float x = fmaf(xy.x, (float)W, -0.5f);
        const float y = fmaf(xy.y, (float)H, -0.5f);
        const float x0f = floorf(x), y0f = floorf(y);
        const float fx = x - x0f, fy = y - y0f;
        const int x0 = (int)x0f, y0 = (int)y0f;

        const int xi0 = min(max(x0, 0), W - 1);
        const int xi1 = min(max(x0 + 1, 0), W - 1);
        const int yi0 = min(max(y0, 0), H - 1);
        const int yi1 = min(max(y0 + 1, 0), H - 1);
        const float mx0 = (x0 >= 0 && x0 < W) ? 1.f : 0.f;
        const float mx1 = (x0 + 1 < W)        ? 1.f : 0.f;
        const float my0 = (y0 >= 0 && y0 < H) ? 1.f : 0.f;
        const float my1 = (y0 + 1 < H)        ? 1.f : 0.f;
        const float gx0 = (1.f - fx) * mx0, gx1 = fx * ((x0 + 1 >= 0) ? mx1 : 0.f);
        const float gy0 = (1.f - fy) * my0, gy1 = fy * ((y0 + 1 >= 0) ? my1 : 0.f);

        const int r0 = (s0 + yi0 * W) * D_H;
        const int r1 = (s0 + yi1 * W) * D_H;
        soff[t] = (int4){r0 + xi0 * D_H, r0 + xi1 * D_H, r1 + xi0 * D_H, r1 + xi1 * D_H};
        swgt[t] = (float4){a * gx0 * gy0, a * gx1 * gy0, a * gx0 * gy1, a * gx1 * gy1};
    }
    __syncthreads();

    const int m = t >> 5, d = t & 31;
    const int b = (int)(tok / LIN);
    const unsigned short* vb = value + ((long)(b * M_H + m)) * LIN * D_H + d;

    float acc = 0.f;
#pragma unroll
    for (int p = 0; p < 16; ++p) {
        const int jj = m * 16 + p;
        const int4   o = soff[jj];
        const float4 wv = swgt[jj];
        acc = fmaf(bf2f(vb[o.x]), wv.x, acc);
        acc = fmaf(bf2f(vb[o.y]), wv.y, acc);
        acc = fmaf(bf2f(vb[o.z]), wv.z, acc);
        acc = fmaf(bf2f(vb[o.w]), wv.w, acc);
    }
    outb[tok * C_DIM + t] = (bf16)acc;
}

// ---------------------------------------------------------------------------
// K4: src2 = outb @ Woutt^T + bout; y = src + src2; LN(y) -> xb bf16
// (byte-identical to round 8)
// ---------------------------------------------------------------------------
__global__ __launch_bounds__(256) void k_post_mfma(const bf16* __restrict__ A,
                                                   const bf16* __restrict__ Bw,
                                                   const float* __restrict__ bout,
                                                   const float* __restrict__ src,
                                                   const float* __restrict__ g_,
                                                   const float* __restrict__ be_,
                                                   bf16* __restrict__ xb) {
    __shared__ bf16 xs[32 * 256];
    __shared__ float yt[32][256];
    GEMM_PROLOG(A, blockIdx.x)

#pragma unroll
    for (int nt = 0; nt < 4; ++nt) {
        const int n = w * 64 + nt * 16 + c0;
        f32x4 a0 = {0.f, 0.f, 0.f, 0.f};
        f32x4 a1 = {0.f, 0.f, 0.f, 0.f};
        const bf16* wrow = Bw + (long)n * 256 + kg * 8;
#pragma unroll
        for (int kc = 0; kc < 8; ++kc) {
            const bf16x8 bfr = *(const bf16x8*)(wrow + kc * 32);
            a0 = __builtin_amdgcn_mfma_f32_16x16x32_bf16(afr[0][kc], bfr, a0, 0, 0, 0);
            a1 = __builtin_amdgcn_mfma_f32_16x16x32_bf16(afr[1][kc], bfr, a1, 0, 0, 0);
        }
        const float bb = bout[n];
#pragma unroll
        for (int r = 0; r < 4; ++r) {
            const int row = kg * 4 + r;
            yt[row][n]      = a0[r] + bb + src[(tok0 + row) * C_DIM + n];
            yt[row + 16][n] = a1[r] + bb + src[(tok0 + row + 16) * C_DIM + n];
        }
    }
    __syncthreads();

    const float4 g4 = ((const float4*)g_)[lane];
    const float4 b4 = ((const float4*)be_)[lane];
#pragma unroll
    for (int rr = 0; rr < 8; ++rr) {
        const int row = w * 8 + rr;
        const float4 y4 = *(const float4*)&yt[row][lane * 4];
        float s1 = y4.x + y4.y + y4.z + y4.w;
        float s2 = y4.x * y4.x + y4.y * y4.y + y4.z * y4.z + y4.w * y4.w;
#pragma unroll
        for (int s = 1; s < 64; s <<= 1) {
            s1 += __shfl_xor(s1, s);
            s2 += __shfl_xor(s2, s);
        }
        const float mean = s1 * (1.f / 256.f);
        const float var  = s2 * (1.f / 256.f) - mean * mean;
        const float inv  = rsqrtf(var + LN_EPS);
        bf16x4 o;
        o.x = (bf16)((y4.x - mean) * inv * g4.x + b4.x);
        o.y = (bf16)((y4.y - mean) * inv * g4.y + b4.y);
        o.z = (bf16)((y4.z - mean) * inv * g4.z + b4.z);
        o.w = (bf16)((y4.w - mean) * inv * g4.w + b4.w);
        *(bf16x4*)(xb + (tok0 + row) * C_DIM + lane * 4) = o;
    }
}

// ---------------------------------------------------------------------------
// K5: fused FFN, 64-token tile (4 m-halves per wave), sequential A/B phases,
// single 32 KB h-chunk buffer. Every W-fragment load feeds 4 MFMAs.
// Accumulation order per output element identical to round 8 -> bit-identical.
// ---------------------------------------------------------------------------
__global__ __launch_bounds__(256, 2) void k_ffn_mfma(const bf16* __restrict__ x,
                                                     const bf16* __restrict__ W1t,
                                                     const float* __restrict__ b1,
                                                     const bf16* __restrict__ W2t,
                                                     const float* __restrict__ b2,
                                                     float* __restrict__ out) {
    __shared__ bf16 hs[64 * 256];   // 32 KB, swizzled: elem ^ ((row&7)<<3)
    const int lane = threadIdx.x & 63, w = threadIdx.x >> 6;
    const int c0 = lane & 15, kg = lane >> 4;
    const long tok0 = (long)blockIdx.x * 64;

    bf16x8 afr[4][8];
#pragma unroll
    for (int mh = 0; mh < 4; ++mh) {
        const bf16* arow = x + (tok0 + mh * 16 + c0) * C_DIM + kg * 8;
#pragma unroll
        for (int kc = 0; kc < 8; ++kc)
            afr[mh][kc] = *(const bf16x8*)(arow + kc * 32);
    }

    f32x4 acc[4][4];
#pragma unroll
    for (int mh = 0; mh < 4; ++mh)
#pragma unroll
        for (int nt = 0; nt < 4; ++nt)
            acc[mh][nt] = (f32x4){0.f, 0.f, 0.f, 0.f};

    for (int c = 0; c < 4; ++c) {
        if (c) __syncthreads();   // prev chunk's Phase-B reads done before overwrite

        // ---- Phase A: h[:, c*256 + w*64 .. +64) for 64 tokens ----
#pragma unroll
        for (int nt = 0; nt < 4; ++nt) {
            const int nl = w * 64 + nt * 16 + c0;    // col within chunk
            const int n  = c * 256 + nl;             // global h col
            f32x4 a[4];
#pragma unroll
            for (int mh = 0; mh < 4; ++mh) a[mh] = (f32x4){0.f, 0.f, 0.f, 0.f};
            const bf16* wrow = W1t + (long)n * 256 + kg * 8;
#pragma unroll
            for (int kc = 0; kc < 8; ++kc) {
                const bf16x8 bfr = *(const bf16x8*)(wrow + kc * 32);
#pragma unroll
                for (int mh = 0; mh < 4; ++mh)
                    a[mh] = __builtin_amdgcn_mfma_f32_16x16x32_bf16(afr[mh][kc], bfr, a[mh], 0, 0, 0);
            }
            const float bb = b1[n];
#pragma unroll
            for (int mh = 0; mh < 4; ++mh) {
#pragma unroll
                for (int r = 0; r < 4; ++r) {
                    const int row = mh * 16 + kg * 4 + r;
                    hs[(row * 256 + nl) ^ ((row & 7) << 3)] = (bf16)fmaxf(a[mh][r] + bb, 0.f);
                }
            }
        }
        __syncthreads();

        // ---- Phase B: accumulate over k in [c*256, c*256+256) ----
#pragma unroll
        for (int kc2 = 0; kc2 < 8; ++kc2) {
            const int kl = kc2 * 32 + kg * 8;        // k within chunk (8-aligned)
            bf16x8 ah[4];
#pragma unroll
            for (int mh = 0; mh < 4; ++mh) {
                const int row = mh * 16 + c0;
                ah[mh] = *(const bf16x8*)&hs[(row * 256 + kl) ^ ((row & 7) << 3)];
            }
#pragma unroll
            for (int nt = 0; nt < 4; ++nt) {
                const int n = w * 64 + nt * 16 + c0;
                const bf16x8 bfr = *(const bf16x8*)(W2t + (long)n * FFN + c * 256 + kl);
#pragma unroll
                for (int mh = 0; mh < 4; ++mh)
                    acc[mh][nt] = __builtin_amdgcn_mfma_f32_16x16x32_bf16(ah[mh], bfr, acc[mh][nt], 0, 0, 0);
            }
        }
    }

#pragma unroll
    for (int nt = 0; nt < 4; ++nt) {
        const int n = w * 64 + nt * 16 + c0;
        const float bb = b2[n];
#pragma unroll
        for (int mh = 0; mh < 4; ++mh) {
#pragma unroll
            for (int r = 0; r < 4; ++r)
                out[(tok0 + mh * 16 + kg * 4 + r) * C_DIM + n] = acc[mh][nt][r] + bb;
        }
    }
}

// ---------------------------------------------------------------------------
extern "C" void kernel_launch(void* const* d_in, const int* in_sizes, int n_in,
                              void* d_out, int out_size, void* d_ws, size_t ws_size,
                              hipStream_t stream) {
    const float* src   = (const float*)d_in[0];
    const float* pos   = (const float*)d_in[1];
    const float* refp  = (const float*)d_in[2];
    const float* Wv    = (const float*)d_in[3];
    const float* bv    = (const float*)d_in[4];
    const float* Wo    = (const float*)d_in[5];
    const float* bo    = (const float*)d_in[6];
    const float* Wa    = (const float*)d_in[7];
    const float* ba    = (const float*)d_in[8];
    const float* Wout  = (const float*)d_in[9];
    const float* bout  = (const float*)d_in[10];
    const float* gamma = (const float*)d_in[11];
    const float* beta  = (const float*)d_in[12];
    const float* W1    = (const float*)d_in[13];
    const float* b1    = (const float*)d_in[14];
    const float* W2    = (const float*)d_in[15];
    const float* b2    = (const float*)d_in[16];

    const size_t N256 = (size_t)NTOK * C_DIM;      // elements
    bf16*  srcb = (bf16*)d_ws;                     // NTOK*256 bf16
    bf16*  qb   = srcb + N256;                     // NTOK*256 bf16
    bf16*  val  = qb + N256;                       // NTOK*256 bf16
    float* loc  = (float*)(val + N256);            // NTOK*256 f32
    float* att  = loc + N256;                      // NTOK*128 f32
    bf16*  Wvt  = (bf16*)(att + (size_t)NTOK * 128);
    bf16*  Wqt  = Wvt + 256 * 256;                 // 384x256 (Wo^T | Wa^T)
    bf16*  Woutt= Wqt + 384 * 256;
    bf16*  W1t  = Woutt + 256 * 256;
    bf16*  W2t  = W1t + (size_t)FFN * C_DIM;
    bf16*  outb = srcb;                            // alias: srcb dead after value GEMM
    bf16*  xb   = qb;                              // alias: qb dead after qloc GEMM

    dim3 blk(256);
    k_prep<<<NCONV + 736, blk, 0, stream>>>(src, pos, srcb, qb,
                                            Wv, Wo, Wa, Wout, W1, W2,
                                            Wvt, Wqt, Woutt, W1t, W2t);
    k_vq  <<<2 * NTILE, blk, 0, stream>>>(srcb, qb, Wvt, bv, val,
                                          Wqt, bo, ba, refp, loc, att);
    k_samp<<<NTOK, blk, 0, stream>>>((const unsigned short*)val, loc, att, outb);
    k_post_mfma<<<NTILE, blk, 0, stream>>>(outb, Woutt, bout, src, gamma, beta, xb);
    k_ffn_mfma <<<NTOK / 64, blk, 0, stream>>>(xb, W1t, b1, W2t, b2, (float*)d_out);
}

// Round 11
// 443.341 us; speedup vs baseline: 1.1133x; 1.1133x over previous
//
#include <hip/hip_runtime.h>
#include <hip/hip_bf16.h>
#include <math.h>

#define B_SZ   2
#define LIN    21760
#define C_DIM  256
#define M_H    8
#define D_H    32
#define NLEV   4
#define NPTS   4
#define FFN    1024
#define NTOK   (B_SZ * LIN)      // 43520
#define NTILE  (NTOK / 32)       // 1360
#define NCONV  (NTOK * C_DIM / 4 / 256)  // 10880
#define LN_EPS 1e-5f

typedef __bf16 bf16;
typedef bf16  bf16x4 __attribute__((ext_vector_type(4)));
typedef bf16  bf16x8 __attribute__((ext_vector_type(8)));
typedef float f32x4  __attribute__((ext_vector_type(4)));

__device__ __constant__ int c_Ht[4] = {128, 64, 32, 16};
__device__ __constant__ int c_Wt[4] = {128, 64, 32, 16};
__device__ __constant__ int c_St[4] = {0, 16384, 20480, 21504};

static __device__ __forceinline__ float bf2f(unsigned short u) {
    union { float f; unsigned int i; } c;
    c.i = ((unsigned int)u) << 16;
    return c.f;
}

// ---------------------------------------------------------------------------
// Prep (merged): blockIdx < NCONV: srcb=bf16(src), qb=bf16(src+pos);
// else: one 32x32 transpose tile of one of the six weight matrices.
// ---------------------------------------------------------------------------
__global__ __launch_bounds__(256) void k_prep(const float* __restrict__ src,
                                              const float* __restrict__ pos,
                                              bf16* __restrict__ srcb,
                                              bf16* __restrict__ qb,
                                              const float* __restrict__ Wv,
                                              const float* __restrict__ Wo,
                                              const float* __restrict__ Wa,
                                              const float* __restrict__ Wout,
                                              const float* __restrict__ W1,
                                              const float* __restrict__ W2,
                                              bf16* __restrict__ Wvt,
                                              bf16* __restrict__ Wqt,
                                              bf16* __restrict__ Woutt,
                                              bf16* __restrict__ W1t,
                                              bf16* __restrict__ W2t) {
    __shared__ float tile[32][33];
    const int bid = blockIdx.x;
    if (bid < NCONV) {
        const int i = bid * 256 + threadIdx.x;
        const float4 s4 = ((const float4*)src)[i];
        const float4 p4 = ((const float4*)pos)[i];
        bf16x4 sb, qb4;
        sb.x = (bf16)s4.x; sb.y = (bf16)s4.y; sb.z = (bf16)s4.z; sb.w = (bf16)s4.w;
        qb4.x = (bf16)(s4.x + p4.x); qb4.y = (bf16)(s4.y + p4.y);
        qb4.z = (bf16)(s4.z + p4.z); qb4.w = (bf16)(s4.w + p4.w);
        ((bf16x4*)srcb)[i] = sb;
        ((bf16x4*)qb)[i]   = qb4;
        return;
    }
    int b = bid - NCONV;
    const float* W; bf16* Wt; int K, N, ntn;
    if      (b < 64)  { W = Wv;   Wt = Wvt;           K = 256;  N = 256;  ntn = 8;            }
    else if (b < 128) { W = Wo;   Wt = Wqt;           K = 256;  N = 256;  ntn = 8;  b -= 64;  }
    else if (b < 160) { W = Wa;   Wt = Wqt + 65536;   K = 256;  N = 128;  ntn = 4;  b -= 128; }
    else if (b < 224) { W = Wout; Wt = Woutt;         K = 256;  N = 256;  ntn = 8;  b -= 160; }
    else if (b < 480) { W = W1;   Wt = W1t;           K = 256;  N = 1024; ntn = 32; b -= 224; }
    else              { W = W2;   Wt = W2t;           K = 1024; N = 256;  ntn = 8;  b -= 480; }

    const int bx = b % ntn;
    const int by = b / ntn;
    const int tx = threadIdx.x & 31, ty = threadIdx.x >> 5;
    const int n0 = bx * 32, k0 = by * 32;
#pragma unroll
    for (int i = 0; i < 32; i += 8)
        tile[ty + i][tx] = W[(long)(k0 + ty + i) * N + n0 + tx];
    __syncthreads();
#pragma unroll
    for (int i = 0; i < 32; i += 8)
        Wt[(long)(n0 + ty + i) * K + k0 + tx] = (bf16)tile[tx][ty + i];
}

// ---------------------------------------------------------------------------
// Shared GEMM prolog: 32-token tile, K=256, A staged+swizzled in LDS.
// (byte-identical math to round 8; BID parameterized for merged dispatch)
// ---------------------------------------------------------------------------
#define GEMM_PROLOG(Aptr, BID)                                                \
    const int t = threadIdx.x;                                                \
    const int lane = t & 63, w = t >> 6;                                      \
    const int c0 = lane & 15, kg = lane >> 4;                                 \
    const long tok0 = (long)(BID) * 32;                                       \
    {                                                                         \
        const bf16x8* src8 = (const bf16x8*)((Aptr) + tok0 * C_DIM);          \
        bf16x8* dst8 = (bf16x8*)xs;                                           \
        for (int i = t; i < 1024; i += 256)                                   \
            dst8[i ^ ((i >> 5) & 7)] = src8[i];                               \
    }                                                                         \
    __syncthreads();                                                          \
    bf16x8 afr[2][8];                                                         \
    _Pragma("unroll")                                                         \
    for (int mh = 0; mh < 2; ++mh) {                                          \
        const int m = mh * 16 + c0;                                           \
        _Pragma("unroll")                                                     \
        for (int kc = 0; kc < 8; ++kc) {                                      \
            const int chunk = m * 32 + kc * 4 + kg;                           \
            afr[mh][kc] = ((const bf16x8*)xs)[chunk ^ (m & 7)];               \
        }                                                                     \
    }

// ---------------------------------------------------------------------------
// K1+K2 merged: blocks [0,NTILE) -> value GEMM; [NTILE,2*NTILE) -> qloc GEMM.
// ---------------------------------------------------------------------------
__global__ __launch_bounds__(256) void k_vq(const bf16* __restrict__ srcb,
                                            const bf16* __restrict__ qbuf,
                                            const bf16* __restrict__ Wvt,
                                            const float* __restrict__ bv,
                                            bf16* __restrict__ value,
                                            const bf16* __restrict__ Wqt,
                                            const float* __restrict__ bo,
                                            const float* __restrict__ ba,
                                            const float* __restrict__ refp,
                                            float* __restrict__ loc,
                                            float* __restrict__ att) {
    __shared__ bf16 xs[32 * 256];
    if (blockIdx.x < NTILE) {
        GEMM_PROLOG(srcb, blockIdx.x)

        const int b = (int)(tok0 / LIN);
        const int qbase = (int)(tok0 - (long)b * LIN);

#pragma unroll
        for (int nt = 0; nt < 4; ++nt) {
            const int n = w * 64 + nt * 16 + c0;
            f32x4 a0 = {0.f, 0.f, 0.f, 0.f};
            f32x4 a1 = {0.f, 0.f, 0.f, 0.f};
            const bf16* wrow = Wvt + (long)n * 256 + kg * 8;
#pragma unroll
            for (int kc = 0; kc < 8; ++kc) {
                const bf16x8 bfr = *(const bf16x8*)(wrow + kc * 32);
                a0 = __builtin_amdgcn_mfma_f32_16x16x32_bf16(afr[0][kc], bfr, a0, 0, 0, 0);
                a1 = __builtin_amdgcn_mfma_f32_16x16x32_bf16(afr[1][kc], bfr, a1, 0, 0, 0);
            }
            const float bb = bv[n];
            const int m = n >> 5, d = n & 31;
            bf16* vb = value + ((long)(b * M_H + m) * LIN) * D_H + d;
#pragma unroll
            for (int r = 0; r < 4; ++r) {
                const int q0 = qbase + kg * 4 + r;
                vb[(long)q0 * D_H]        = (bf16)(a0[r] + bb);
                vb[(long)(q0 + 16) * D_H] = (bf16)(a1[r] + bb);
            }
        }
    } else {
        GEMM_PROLOG(qbuf, blockIdx.x - NTILE)

#pragma unroll
        for (int nt = 0; nt < 6; ++nt) {
            const int n = w * 96 + nt * 16 + c0;
            f32x4 a0 = {0.f, 0.f, 0.f, 0.f};
            f32x4 a1 = {0.f, 0.f, 0.f, 0.f};
            const bf16* wrow = Wqt + (long)n * 256 + kg * 8;
#pragma unroll
            for (int kc = 0; kc < 8; ++kc) {
                const bf16x8 bfr = *(const bf16x8*)(wrow + kc * 32);
                a0 = __builtin_amdgcn_mfma_f32_16x16x32_bf16(afr[0][kc], bfr, a0, 0, 0, 0);
                a1 = __builtin_amdgcn_mfma_f32_16x16x32_bf16(afr[1][kc], bfr, a1, 0, 0, 0);
            }
            if (n < 256) {
                const int l = (n >> 3) & 3;
                const int c = n & 1;
                const float rnorm = 1.f / ((c == 0) ? (float)c_Wt[l] : (float)c_Ht[l]);
                const float bb = bo[n];
#pragma unroll
                for (int r = 0; r < 4; ++r) {
                    const long t0 = tok0 + kg * 4 + r;
                    const long t1 = t0 + 16;
                    loc[t0 * C_DIM + n] = refp[t0 * 8 + l * 2 + c] + (a0[r] + bb) * rnorm;
                    loc[t1 * C_DIM + n] = refp[t1 * 8 + l * 2 + c] + (a1[r] + bb) * rnorm;
                }
            } else {
                const int j = n - 256;
                const float bb = ba[j];
#pragma unroll
                for (int r = 0; r < 4; ++r) {
                    const long t0 = tok0 + kg * 4 + r;
                    att[t0 * 128 + j]        = a0[r] + bb;
                    att[(t0 + 16) * 128 + j] = a1[r] + bb;
                }
            }
        }
    }
}

// ---------------------------------------------------------------------------
// K3: deformable sampling, two-phase (byte-identical to round 8)
// ---------------------------------------------------------------------------
__global__ __launch_bounds__(256) void k_samp(const unsigned short* __restrict__ value,
                                              const float* __restrict__ loc,
                                              const float* __restrict__ att,
                                              bf16* __restrict__ outb) {
    __shared__ int4   soff[128];
    __shared__ float4 swgt[128];
    const int t = threadIdx.x;
    const long tok = blockIdx.x;

    if (t < 128) {
        const float lg = att[tok * 128 + t];
        float mx = lg;
#pragma unroll
        for (int s = 1; s < 16; s <<= 1) mx = fmaxf(mx, __shfl_xor(mx, s));
        const float e = expf(lg - mx);
        float sm = e;
#pragma unroll
        for (int s = 1; s < 16; s <<= 1) sm += __shfl_xor(sm, s);
        const float a = e / sm;

        const float2 xy = ((const float2*)loc)[tok * 128 + t];
        const int l = (t >> 2) & 3;
        const int H = c_Ht[l], W = c_Wt[l], s0 = c_St[l];
        const float x = fmaf(xy.x, (float)W, -0.5f);
        const float y = fmaf(xy.y, (float)H, -0.5f);
        const float x0f = floorf(x), y0f = floorf(y);
        const float fx = x - x0f, fy = y - y0f;
        const int x0 = (int)x0f, y0 = (int)y0f;

        const int xi0 = min(max(x0, 0), W - 1);
        const int xi1 = min(max(x0 + 1, 0), W - 1);
        const int yi0 = min(max(y0, 0), H - 1);
        const int yi1 = min(max(y0 + 1, 0), H - 1);
        const float mx0 = (x0 >= 0 && x0 < W) ? 1.f : 0.f;
        const float mx1 = (x0 + 1 < W)        ? 1.f : 0.f;
        const float my0 = (y0 >= 0 && y0 < H) ? 1.f : 0.f;
        const float my1 = (y0 + 1 < H)        ? 1.f : 0.f;
        const float gx0 = (1.f - fx) * mx0, gx1 = fx * ((x0 + 1 >= 0) ? mx1 : 0.f);
        const float gy0 = (1.f - fy) * my0, gy1 = fy * ((y0 + 1 >= 0) ? my1 : 0.f);

        const int r0 = (s0 + yi0 * W) * D_H;
        const int r1 = (s0 + yi1 * W) * D_H;
        soff[t] = (int4){r0 + xi0 * D_H, r0 + xi1 * D_H, r1 + xi0 * D_H, r1 + xi1 * D_H};
        swgt[t] = (float4){a * gx0 * gy0, a * gx1 * gy0, a * gx0 * gy1, a * gx1 * gy1};
    }
    __syncthreads();

    const int m = t >> 5, d = t & 31;
    const int b = (int)(tok / LIN);
    const unsigned short* vb = value + ((long)(b * M_H + m)) * LIN * D_H + d;

    float acc = 0.f;
#pragma unroll
    for (int p = 0; p < 16; ++p) {
        const int jj = m * 16 + p;
        const int4   o = soff[jj];
        const float4 wv = swgt[jj];
        acc = fmaf(bf2f(vb[o.x]), wv.x, acc);
        acc = fmaf(bf2f(vb[o.y]), wv.y, acc);
        acc = fmaf(bf2f(vb[o.z]), wv.z, acc);
        acc = fmaf(bf2f(vb[o.w]), wv.w, acc);
    }
    outb[tok * C_DIM + t] = (bf16)acc;
}

// ---------------------------------------------------------------------------
// K4: src2 = outb @ Woutt^T + bout; y = src + src2; LN(y) -> xb bf16
// (byte-identical to round 8)
// ---------------------------------------------------------------------------
__global__ __launch_bounds__(256) void k_post_mfma(const bf16* __restrict__ A,
                                                   const bf16* __restrict__ Bw,
                                                   const float* __restrict__ bout,
                                                   const float* __restrict__ src,
                                                   const float* __restrict__ g_,
                                                   const float* __restrict__ be_,
                                                   bf16* __restrict__ xb) {
    __shared__ bf16 xs[32 * 256];
    __shared__ float yt[32][256];
    GEMM_PROLOG(A, blockIdx.x)

#pragma unroll
    for (int nt = 0; nt < 4; ++nt) {
        const int n = w * 64 + nt * 16 + c0;
        f32x4 a0 = {0.f, 0.f, 0.f, 0.f};
        f32x4 a1 = {0.f, 0.f, 0.f, 0.f};
        const bf16* wrow = Bw + (long)n * 256 + kg * 8;
#pragma unroll
        for (int kc = 0; kc < 8; ++kc) {
            const bf16x8 bfr = *(const bf16x8*)(wrow + kc * 32);
            a0 = __builtin_amdgcn_mfma_f32_16x16x32_bf16(afr[0][kc], bfr, a0, 0, 0, 0);
            a1 = __builtin_amdgcn_mfma_f32_16x16x32_bf16(afr[1][kc], bfr, a1, 0, 0, 0);
        }
        const float bb = bout[n];
#pragma unroll
        for (int r = 0; r < 4; ++r) {
            const int row = kg * 4 + r;
            yt[row][n]      = a0[r] + bb + src[(tok0 + row) * C_DIM + n];
            yt[row + 16][n] = a1[r] + bb + src[(tok0 + row + 16) * C_DIM + n];
        }
    }
    __syncthreads();

    const float4 g4 = ((const float4*)g_)[lane];
    const float4 b4 = ((const float4*)be_)[lane];
#pragma unroll
    for (int rr = 0; rr < 8; ++rr) {
        const int row = w * 8 + rr;
        const float4 y4 = *(const float4*)&yt[row][lane * 4];
        float s1 = y4.x + y4.y + y4.z + y4.w;
        float s2 = y4.x * y4.x + y4.y * y4.y + y4.z * y4.z + y4.w * y4.w;
#pragma unroll
        for (int s = 1; s < 64; s <<= 1) {
            s1 += __shfl_xor(s1, s);
            s2 += __shfl_xor(s2, s);
        }
        const float mean = s1 * (1.f / 256.f);
        const float var  = s2 * (1.f / 256.f) - mean * mean;
        const float inv  = rsqrtf(var + LN_EPS);
        bf16x4 o;
        o.x = (bf16)((y4.x - mean) * inv * g4.x + b4.x);
        o.y = (bf16)((y4.y - mean) * inv * g4.y + b4.y);
        o.z = (bf16)((y4.z - mean) * inv * g4.z + b4.z);
        o.w = (bf16)((y4.w - mean) * inv * g4.w + b4.w);
        *(bf16x4*)(xb + (tok0 + row) * C_DIM + lane * 4) = o;
    }
}

// ---------------------------------------------------------------------------
// K5: fused FFN, 32-token tile, A-fragments direct from global, h chunked
// as 2 x (32x512) through one 32 KB LDS buffer (3 barriers total).
// Accumulation order per output element identical to round 8 -> bit-identical.
// ---------------------------------------------------------------------------
__global__ __launch_bounds__(256) void k_ffn_mfma(const bf16* __restrict__ x,
                                                  const bf16* __restrict__ W1t,
                                                  const float* __restrict__ b1,
                                                  const bf16* __restrict__ W2t,
                                                  const float* __restrict__ b2,
                                                  float* __restrict__ out) {
    __shared__ bf16 hs[32 * 512];   // 32 KB, swizzled: elem ^ ((row&7)<<3)
    const int lane = threadIdx.x & 63, w = threadIdx.x >> 6;
    const int c0 = lane & 15, kg = lane >> 4;
    const long tok0 = (long)blockIdx.x * 32;

    bf16x8 afr[2][8];
#pragma unroll
    for (int mh = 0; mh < 2; ++mh) {
        const bf16* arow = x + (tok0 + mh * 16 + c0) * C_DIM + kg * 8;
#pragma unroll
        for (int kc = 0; kc < 8; ++kc)
            afr[mh][kc] = *(const bf16x8*)(arow + kc * 32);
    }

    f32x4 acc[2][4];
#pragma unroll
    for (int mh = 0; mh < 2; ++mh)
#pragma unroll
        for (int nt = 0; nt < 4; ++nt)
            acc[mh][nt] = (f32x4){0.f, 0.f, 0.f, 0.f};

    for (int c = 0; c < 2; ++c) {
        if (c) __syncthreads();   // prev chunk's Phase-B reads done before overwrite

        // ---- Phase A: h[:, c*512 + w*128 .. +128) ----
#pragma unroll
        for (int nt = 0; nt < 8; ++nt) {
            const int nl = w * 128 + nt * 16 + c0;   // col within chunk
            const int n  = c * 512 + nl;             // global h col
            f32x4 a0 = {0.f, 0.f, 0.f, 0.f};
            f32x4 a1 = {0.f, 0.f, 0.f, 0.f};
            const bf16* wrow = W1t + (long)n * 256 + kg * 8;
#pragma unroll
            for (int kc = 0; kc < 8; ++kc) {
                const bf16x8 bfr = *(const bf16x8*)(wrow + kc * 32);
                a0 = __builtin_amdgcn_mfma_f32_16x16x32_bf16(afr[0][kc], bfr, a0, 0, 0, 0);
                a1 = __builtin_amdgcn_mfma_f32_16x16x32_bf16(afr[1][kc], bfr, a1, 0, 0, 0);
            }
            const float bb = b1[n];
#pragma unroll
            for (int r = 0; r < 4; ++r) {
                const int row0 = kg * 4 + r;
                hs[(row0 * 512 + nl)        ^ ((row0 & 7) << 3)] = (bf16)fmaxf(a0[r] + bb, 0.f);
                hs[((row0 + 16) * 512 + nl) ^ ((row0 & 7) << 3)] = (bf16)fmaxf(a1[r] + bb, 0.f);
            }
        }
        __syncthreads();

        // ---- Phase B: accumulate over k in [c*512, c*512+512) ----
#pragma unroll
        for (int kc2 = 0; kc2 < 16; ++kc2) {
            const int kl = kc2 * 32 + kg * 8;        // k within chunk (8-aligned)
            const bf16x8 a0 = *(const bf16x8*)&hs[(c0 * 512 + kl)        ^ ((c0 & 7) << 3)];
            const bf16x8 a1 = *(const bf16x8*)&hs[((c0 + 16) * 512 + kl) ^ ((c0 & 7) << 3)];
#pragma unroll
            for (int nt = 0; nt < 4; ++nt) {
                const int n = w * 64 + nt * 16 + c0;
                const bf16x8 bfr = *(const bf16x8*)(W2t + (long)n * FFN + c * 512 + kl);
                acc[0][nt] = __builtin_amdgcn_mfma_f32_16x16x32_bf16(a0, bfr, acc[0][nt], 0, 0, 0);
                acc[1][nt] = __builtin_amdgcn_mfma_f32_16x16x32_bf16(a1, bfr, acc[1][nt], 0, 0, 0);
            }
        }
    }

#pragma unroll
    for (int nt = 0; nt < 4; ++nt) {
        const int n = w * 64 + nt * 16 + c0;
        const float bb = b2[n];
#pragma unroll
        for (int r = 0; r < 4; ++r) {
            out[(tok0 + kg * 4 + r) * C_DIM + n]      = acc[0][nt][r] + bb;
            out[(tok0 + 16 + kg * 4 + r) * C_DIM + n] = acc[1][nt][r] + bb;
        }
    }
}

// ---------------------------------------------------------------------------
extern "C" void kernel_launch(void* const* d_in, const int* in_sizes, int n_in,
                              void* d_out, int out_size, void* d_ws, size_t ws_size,
                              hipStream_t stream) {
    const float* src   = (const float*)d_in[0];
    const float* pos   = (const float*)d_in[1];
    const float* refp  = (const float*)d_in[2];
    const float* Wv    = (const float*)d_in[3];
    const float* bv    = (const float*)d_in[4];
    const float* Wo    = (const float*)d_in[5];
    const float* bo    = (const float*)d_in[6];
    const float* Wa    = (const float*)d_in[7];
    const float* ba    = (const float*)d_in[8];
    const float* Wout  = (const float*)d_in[9];
    const float* bout  = (const float*)d_in[10];
    const float* gamma = (const float*)d_in[11];
    const float* beta  = (const float*)d_in[12];
    const float* W1    = (const float*)d_in[13];
    const float* b1    = (const float*)d_in[14];
    const float* W2    = (const float*)d_in[15];
    const float* b2    = (const float*)d_in[16];

    const size_t N256 = (size_t)NTOK * C_DIM;      // elements
    bf16*  srcb = (bf16*)d_ws;                     // NTOK*256 bf16
    bf16*  qb   = srcb + N256;                     // NTOK*256 bf16
    bf16*  val  = qb + N256;                       // NTOK*256 bf16
    float* loc  = (float*)(val + N256);            // NTOK*256 f32
    float* att  = loc + N256;                      // NTOK*128 f32
    bf16*  Wvt  = (bf16*)(att + (size_t)NTOK * 128);
    bf16*  Wqt  = Wvt + 256 * 256;                 // 384x256 (Wo^T | Wa^T)
    bf16*  Woutt= Wqt + 384 * 256;
    bf16*  W1t  = Woutt + 256 * 256;
    bf16*  W2t  = W1t + (size_t)FFN * C_DIM;
    bf16*  outb = srcb;                            // alias: srcb dead after value GEMM
    bf16*  xb   = qb;                              // alias: qb dead after qloc GEMM

    dim3 blk(256);
    k_prep<<<NCONV + 736, blk, 0, stream>>>(src, pos, srcb, qb,
                                            Wv, Wo, Wa, Wout, W1, W2,
                                            Wvt, Wqt, Woutt, W1t, W2t);
    k_vq  <<<2 * NTILE, blk, 0, stream>>>(srcb, qb, Wvt, bv, val,
                                          Wqt, bo, ba, refp, loc, att);
    k_samp<<<NTOK, blk, 0, stream>>>((const unsigned short*)val, loc, att, outb);
    k_post_mfma<<<NTILE, blk, 0, stream>>>(outb, Woutt, bout, src, gamma, beta, xb);
    k_ffn_mfma <<<NTILE, blk, 0, stream>>>(xb, W1t, b1, W2t, b2, (float*)d_out);
}

// Round 13
// 415.202 us; speedup vs baseline: 1.1888x; 1.0678x over previous
//
#include <hip/hip_runtime.h>
#include <hip/hip_bf16.h>
#include <math.h>

#define B_SZ   2
#define LIN    21760
#define C_DIM  256
#define M_H    8
#define D_H    32
#define NLEV   4
#define NPTS   4
#define FFN    1024
#define NTOK   (B_SZ * LIN)      // 43520
#define NTILE  (NTOK / 32)       // 1360
#define NCONV  (NTOK * C_DIM / 4 / 256)  // 10880
#define LN_EPS 1e-5f

typedef __bf16 bf16;
typedef bf16  bf16x4 __attribute__((ext_vector_type(4)));
typedef bf16  bf16x8 __attribute__((ext_vector_type(8)));
typedef float f32x4  __attribute__((ext_vector_type(4)));

__device__ __constant__ int c_Ht[4] = {128, 64, 32, 16};
__device__ __constant__ int c_Wt[4] = {128, 64, 32, 16};
__device__ __constant__ int c_St[4] = {0, 16384, 20480, 21504};

static __device__ __forceinline__ float bf2f(unsigned short u) {
    union { float f; unsigned int i; } c;
    c.i = ((unsigned int)u) << 16;
    return c.f;
}

// ---------------------------------------------------------------------------
// Prep (merged): blockIdx < NCONV: srcb=bf16(src), qb=bf16(src+pos);
// else: one 32x32 transpose tile of one of the six weight matrices.
// ---------------------------------------------------------------------------
__global__ __launch_bounds__(256) void k_prep(const float* __restrict__ src,
                                              const float* __restrict__ pos,
                                              bf16* __restrict__ srcb,
                                              bf16* __restrict__ qb,
                                              const float* __restrict__ Wv,
                                              const float* __restrict__ Wo,
                                              const float* __restrict__ Wa,
                                              const float* __restrict__ Wout,
                                              const float* __restrict__ W1,
                                              const float* __restrict__ W2,
                                              bf16* __restrict__ Wvt,
                                              bf16* __restrict__ Wqt,
                                              bf16* __restrict__ Woutt,
                                              bf16* __restrict__ W1t,
                                              bf16* __restrict__ W2t) {
    __shared__ float tile[32][33];
    const int bid = blockIdx.x;
    if (bid < NCONV) {
        const int i = bid * 256 + threadIdx.x;
        const float4 s4 = ((const float4*)src)[i];
        const float4 p4 = ((const float4*)pos)[i];
        bf16x4 sb, qb4;
        sb.x = (bf16)s4.x; sb.y = (bf16)s4.y; sb.z = (bf16)s4.z; sb.w = (bf16)s4.w;
        qb4.x = (bf16)(s4.x + p4.x); qb4.y = (bf16)(s4.y + p4.y);
        qb4.z = (bf16)(s4.z + p4.z); qb4.w = (bf16)(s4.w + p4.w);
        ((bf16x4*)srcb)[i] = sb;
        ((bf16x4*)qb)[i]   = qb4;
        return;
    }
    int b = bid - NCONV;
    const float* W; bf16* Wt; int K, N, ntn;
    if      (b < 64)  { W = Wv;   Wt = Wvt;           K = 256;  N = 256;  ntn = 8;            }
    else if (b < 128) { W = Wo;   Wt = Wqt;           K = 256;  N = 256;  ntn = 8;  b -= 64;  }
    else if (b < 160) { W = Wa;   Wt = Wqt + 65536;   K = 256;  N = 128;  ntn = 4;  b -= 128; }
    else if (b < 224) { W = Wout; Wt = Woutt;         K = 256;  N = 256;  ntn = 8;  b -= 160; }
    else if (b < 480) { W = W1;   Wt = W1t;           K = 256;  N = 1024; ntn = 32; b -= 224; }
    else              { W = W2;   Wt = W2t;           K = 1024; N = 256;  ntn = 8;  b -= 480; }

    const int bx = b % ntn;
    const int by = b / ntn;
    const int tx = threadIdx.x & 31, ty = threadIdx.x >> 5;
    const int n0 = bx * 32, k0 = by * 32;
#pragma unroll
    for (int i = 0; i < 32; i += 8)
        tile[ty + i][tx] = W[(long)(k0 + ty + i) * N + n0 + tx];
    __syncthreads();
#pragma unroll
    for (int i = 0; i < 32; i += 8)
        Wt[(long)(n0 + ty + i) * K + k0 + tx] = (bf16)tile[tx][ty + i];
}

// ---------------------------------------------------------------------------
// Shared GEMM prolog: 32-token tile, K=256, A staged+swizzled in LDS.
// ---------------------------------------------------------------------------
#define GEMM_PROLOG(Aptr, BID)                                                \
    const int t = threadIdx.x;                                                \
    const int lane = t & 63, w = t >> 6;                                      \
    const int c0 = lane & 15, kg = lane >> 4;                                 \
    const long tok0 = (long)(BID) * 32;                                       \
    {                                                                         \
        const bf16x8* src8 = (const bf16x8*)((Aptr) + tok0 * C_DIM);          \
        bf16x8* dst8 = (bf16x8*)xs;                                           \
        for (int i = t; i < 1024; i += 256)                                   \
            dst8[i ^ ((i >> 5) & 7)] = src8[i];                               \
    }                                                                         \
    __syncthreads();                                                          \
    bf16x8 afr[2][8];                                                         \
    _Pragma("unroll")                                                         \
    for (int mh = 0; mh < 2; ++mh) {                                          \
        const int m = mh * 16 + c0;                                           \
        _Pragma("unroll")                                                     \
        for (int kc = 0; kc < 8; ++kc) {                                      \
            const int chunk = m * 32 + kc * 4 + kg;                           \
            afr[mh][kc] = ((const bf16x8*)xs)[chunk ^ (m & 7)];               \
        }                                                                     \
    }

// ---------------------------------------------------------------------------
// K1+K2 merged: blocks [0,NTILE) -> value GEMM; [NTILE,2*NTILE) -> qloc GEMM.
// ---------------------------------------------------------------------------
__global__ __launch_bounds__(256) void k_vq(const bf16* __restrict__ srcb,
                                            const bf16* __restrict__ qbuf,
                                            const bf16* __restrict__ Wvt,
                                            const float* __restrict__ bv,
                                            bf16* __restrict__ value,
                                            const bf16* __restrict__ Wqt,
                                            const float* __restrict__ bo,
                                            const float* __restrict__ ba,
                                            const float* __restrict__ refp,
                                            float* __restrict__ loc,
                                            float* __restrict__ att) {
    __shared__ bf16 xs[32 * 256];
    if (blockIdx.x < NTILE) {
        GEMM_PROLOG(srcb, blockIdx.x)

        const int b = (int)(tok0 / LIN);
        const int qbase = (int)(tok0 - (long)b * LIN);

#pragma unroll
        for (int nt = 0; nt < 4; ++nt) {
            const int n = w * 64 + nt * 16 + c0;
            f32x4 a0 = {0.f, 0.f, 0.f, 0.f};
            f32x4 a1 = {0.f, 0.f, 0.f, 0.f};
            const bf16* wrow = Wvt + (long)n * 256 + kg * 8;
#pragma unroll
            for (int kc = 0; kc < 8; ++kc) {
                const bf16x8 bfr = *(const bf16x8*)(wrow + kc * 32);
                a0 = __builtin_amdgcn_mfma_f32_16x16x32_bf16(afr[0][kc], bfr, a0, 0, 0, 0);
                a1 = __builtin_amdgcn_mfma_f32_16x16x32_bf16(afr[1][kc], bfr, a1, 0, 0, 0);
            }
            const float bb = bv[n];
            const int m = n >> 5, d = n & 31;
            bf16* vb = value + ((long)(b * M_H + m) * LIN) * D_H + d;
#pragma unroll
            for (int r = 0; r < 4; ++r) {
                const int q0 = qbase + kg * 4 + r;
                vb[(long)q0 * D_H]        = (bf16)(a0[r] + bb);
                vb[(long)(q0 + 16) * D_H] = (bf16)(a1[r] + bb);
            }
        }
    } else {
        GEMM_PROLOG(qbuf, blockIdx.x - NTILE)

#pragma unroll
        for (int nt = 0; nt < 6; ++nt) {
            const int n = w * 96 + nt * 16 + c0;
            f32x4 a0 = {0.f, 0.f, 0.f, 0.f};
            f32x4 a1 = {0.f, 0.f, 0.f, 0.f};
            const bf16* wrow = Wqt + (long)n * 256 + kg * 8;
#pragma unroll
            for (int kc = 0; kc < 8; ++kc) {
                const bf16x8 bfr = *(const bf16x8*)(wrow + kc * 32);
                a0 = __builtin_amdgcn_mfma_f32_16x16x32_bf16(afr[0][kc], bfr, a0, 0, 0, 0);
                a1 = __builtin_amdgcn_mfma_f32_16x16x32_bf16(afr[1][kc], bfr, a1, 0, 0, 0);
            }
            if (n < 256) {
                const int l = (n >> 3) & 3;
                const int c = n & 1;
                const float rnorm = 1.f / ((c == 0) ? (float)c_Wt[l] : (float)c_Ht[l]);
                const float bb = bo[n];
#pragma unroll
                for (int r = 0; r < 4; ++r) {
                    const long t0 = tok0 + kg * 4 + r;
                    const long t1 = t0 + 16;
                    loc[t0 * C_DIM + n] = refp[t0 * 8 + l * 2 + c] + (a0[r] + bb) * rnorm;
                    loc[t1 * C_DIM + n] = refp[t1 * 8 + l * 2 + c] + (a1[r] + bb) * rnorm;
                }
            } else {
                const int j = n - 256;
                const float bb = ba[j];
#pragma unroll
                for (int r = 0; r < 4; ++r) {
                    const long t0 = tok0 + kg * 4 + r;
                    att[t0 * 128 + j]        = a0[r] + bb;
                    att[(t0 + 16) * 128 + j] = a1[r] + bb;
                }
            }
        }
    }
}

// ---------------------------------------------------------------------------
// K3: deformable sampling, two-phase (byte-identical to round 8)
// ---------------------------------------------------------------------------
__global__ __launch_bounds__(256) void k_samp(const unsigned short* __restrict__ value,
                                              const float* __restrict__ loc,
                                              const float* __restrict__ att,
                                              bf16* __restrict__ outb) {
    __shared__ int4   soff[128];
    __shared__ float4 swgt[128];
    const int t = threadIdx.x;
    const long tok = blockIdx.x;

    if (t < 128) {
        const float lg = att[tok * 128 + t];
        float mx = lg;
#pragma unroll
        for (int s = 1; s < 16; s <<= 1) mx = fmaxf(mx, __shfl_xor(mx, s));
        const float e = expf(lg - mx);
        float sm = e;
#pragma unroll
        for (int s = 1; s < 16; s <<= 1) sm += __shfl_xor(sm, s);
        const float a = e / sm;

        const float2 xy = ((const float2*)loc)[tok * 128 + t];
        const int l = (t >> 2) & 3;
        const int H = c_Ht[l], W = c_Wt[l], s0 = c_St[l];
        const float x = fmaf(xy.x, (float)W, -0.5f);
        const float y = fmaf(xy.y, (float)H, -0.5f);
        const float x0f = floorf(x), y0f = floorf(y);
        const float fx = x - x0f, fy = y - y0f;
        const int x0 = (int)x0f, y0 = (int)y0f;

        const int xi0 = min(max(x0, 0), W - 1);
        const int xi1 = min(max(x0 + 1, 0), W - 1);
        const int yi0 = min(max(y0, 0), H - 1);
        const int yi1 = min(max(y0 + 1, 0), H - 1);
        const float mx0 = (x0 >= 0 && x0 < W) ? 1.f : 0.f;
        const float mx1 = (x0 + 1 < W)        ? 1.f : 0.f;
        const float my0 = (y0 >= 0 && y0 < H) ? 1.f : 0.f;
        const float my1 = (y0 + 1 < H)        ? 1.f : 0.f;
        const float gx0 = (1.f - fx) * mx0, gx1 = fx * ((x0 + 1 >= 0) ? mx1 : 0.f);
        const float gy0 = (1.f - fy) * my0, gy1 = fy * ((y0 + 1 >= 0) ? my1 : 0.f);

        const int r0 = (s0 + yi0 * W) * D_H;
        const int r1 = (s0 + yi1 * W) * D_H;
        soff[t] = (int4){r0 + xi0 * D_H, r0 + xi1 * D_H, r1 + xi0 * D_H, r1 + xi1 * D_H};
        swgt[t] = (float4){a * gx0 * gy0, a * gx1 * gy0, a * gx0 * gy1, a * gx1 * gy1};
    }
    __syncthreads();

    const int m = t >> 5, d = t & 31;
    const int b = (int)(tok / LIN);
    const unsigned short* vb = value + ((long)(b * M_H + m)) * LIN * D_H + d;

    float acc = 0.f;
#pragma unroll
    for (int p = 0; p < 16; ++p) {
        const int jj = m * 16 + p;
        const int4   o = soff[jj];
        const float4 wv = swgt[jj];
        acc = fmaf(bf2f(vb[o.x]), wv.x, acc);
        acc = fmaf(bf2f(vb[o.y]), wv.y, acc);
        acc = fmaf(bf2f(vb[o.z]), wv.z, acc);
        acc = fmaf(bf2f(vb[o.w]), wv.w, acc);
    }
    outb[tok * C_DIM + t] = (bf16)acc;
}

// ---------------------------------------------------------------------------
// K4: src2 = outb @ Woutt^T + bout; y = src + src2; LN(y) -> xb bf16
// (byte-identical to round 9)
// ---------------------------------------------------------------------------
__global__ __launch_bounds__(256) void k_post_mfma(const bf16* __restrict__ A,
                                                   const bf16* __restrict__ Bw,
                                                   const float* __restrict__ bout,
                                                   const float* __restrict__ src,
                                                   const float* __restrict__ g_,
                                                   const float* __restrict__ be_,
                                                   bf16* __restrict__ xb) {
    __shared__ bf16 xs[32 * 256];
    __shared__ float yt[32][256];
    GEMM_PROLOG(A, blockIdx.x)

#pragma unroll
    for (int nt = 0; nt < 4; ++nt) {
        const int n = w * 64 + nt * 16 + c0;
        f32x4 a0 = {0.f, 0.f, 0.f, 0.f};
        f32x4 a1 = {0.f, 0.f, 0.f, 0.f};
        const bf16* wrow = Bw + (long)n * 256 + kg * 8;
#pragma unroll
        for (int kc = 0; kc < 8; ++kc) {
            const bf16x8 bfr = *(const bf16x8*)(wrow + kc * 32);
            a0 = __builtin_amdgcn_mfma_f32_16x16x32_bf16(afr[0][kc], bfr, a0, 0, 0, 0);
            a1 = __builtin_amdgcn_mfma_f32_16x16x32_bf16(afr[1][kc], bfr, a1, 0, 0, 0);
        }
        const float bb = bout[n];
#pragma unroll
        for (int r = 0; r < 4; ++r) {
            const int row = kg * 4 + r;
            yt[row][n]      = a0[r] + bb + src[(tok0 + row) * C_DIM + n];
            yt[row + 16][n] = a1[r] + bb + src[(tok0 + row + 16) * C_DIM + n];
        }
    }
    __syncthreads();

    const float4 g4 = ((const float4*)g_)[lane];
    const float4 b4 = ((const float4*)be_)[lane];
#pragma unroll
    for (int rr = 0; rr < 8; ++rr) {
        const int row = w * 8 + rr;
        const float4 y4 = *(const float4*)&yt[row][lane * 4];
        float s1 = y4.x + y4.y + y4.z + y4.w;
        float s2 = y4.x * y4.x + y4.y * y4.y + y4.z * y4.z + y4.w * y4.w;
#pragma unroll
        for (int s = 1; s < 64; s <<= 1) {
            s1 += __shfl_xor(s1, s);
            s2 += __shfl_xor(s2, s);
        }
        const float mean = s1 * (1.f / 256.f);
        const float var  = s2 * (1.f / 256.f) - mean * mean;
        const float inv  = rsqrtf(var + LN_EPS);
        bf16x4 o;
        o.x = (bf16)((y4.x - mean) * inv * g4.x + b4.x);
        o.y = (bf16)((y4.y - mean) * inv * g4.y + b4.y);
        o.z = (bf16)((y4.z - mean) * inv * g4.z + b4.z);
        o.w = (bf16)((y4.w - mean) * inv * g4.w + b4.w);
        *(bf16x4*)(xb + (tok0 + row) * C_DIM + lane * 4) = o;
    }
}

// ---------------------------------------------------------------------------
// K5: fused FFN with bf16 MFMA, h chunked through a 16 KB LDS tile.
// (byte-identical to round 8's k_ffn_mfma — best measured: 188 us)
// ---------------------------------------------------------------------------
__global__ __launch_bounds__(256) void k_ffn_mfma(const bf16* __restrict__ x,
                                                  const bf16* __restrict__ W1t,
                                                  const float* __restrict__ b1,
                                                  const bf16* __restrict__ W2t,
                                                  const float* __restrict__ b2,
                                                  float* __restrict__ out) {
    __shared__ bf16 xs[32 * 256];   // 16 KB staging
    __shared__ bf16 hs[32 * 256];   // 16 KB h-chunk, swizzled
    GEMM_PROLOG(x, blockIdx.x)

    f32x4 acc[2][4];
#pragma unroll
    for (int mh = 0; mh < 2; ++mh)
#pragma unroll
        for (int nt = 0; nt < 4; ++nt)
            acc[mh][nt] = (f32x4){0.f, 0.f, 0.f, 0.f};

    for (int c = 0; c < 4; ++c) {
        if (c) __syncthreads();   // prev chunk's Phase-B reads done before overwrite

        // ---- Phase A: h[:, c*256 + w*64 .. +64) ----
#pragma unroll
        for (int nt = 0; nt < 4; ++nt) {
            const int nl = w * 64 + nt * 16 + c0;    // col within chunk
            const int n  = c * 256 + nl;             // global h col
            f32x4 a0 = {0.f, 0.f, 0.f, 0.f};
            f32x4 a1 = {0.f, 0.f, 0.f, 0.f};
            const bf16* wrow = W1t + (long)n * 256 + kg * 8;
#pragma unroll
            for (int kc = 0; kc < 8; ++kc) {
                const bf16x8 bfr = *(const bf16x8*)(wrow + kc * 32);
                a0 = __builtin_amdgcn_mfma_f32_16x16x32_bf16(afr[0][kc], bfr, a0, 0, 0, 0);
                a1 = __builtin_amdgcn_mfma_f32_16x16x32_bf16(afr[1][kc], bfr, a1, 0, 0, 0);
            }
            const float bb = b1[n];
#pragma unroll
            for (int r = 0; r < 4; ++r) {
                const int row0 = kg * 4 + r;
                hs[(row0 * 256 + nl)        ^ ((row0 & 7) << 3)] = (bf16)fmaxf(a0[r] + bb, 0.f);
                hs[((row0 + 16) * 256 + nl) ^ ((row0 & 7) << 3)] = (bf16)fmaxf(a1[r] + bb, 0.f);
            }
        }
        __syncthreads();

        // ---- Phase B: accumulate over k in [c*256, c*256+256) ----
#pragma unroll
        for (int kc2 = 0; kc2 < 8; ++kc2) {
            const int kl = kc2 * 32 + kg * 8;        // k within chunk (8-aligned)
            const bf16x8 a0 = *(const bf16x8*)&hs[(c0 * 256 + kl)        ^ ((c0 & 7) << 3)];
            const bf16x8 a1 = *(const bf16x8*)&hs[((c0 + 16) * 256 + kl) ^ ((c0 & 7) << 3)];
#pragma unroll
            for (int nt = 0; nt < 4; ++nt) {
                const int n = w * 64 + nt * 16 + c0;
                const bf16x8 bfr = *(const bf16x8*)(W2t + (long)n * FFN + c * 256 + kl);
                acc[0][nt] = __builtin_amdgcn_mfma_f32_16x16x32_bf16(a0, bfr, acc[0][nt], 0, 0, 0);
                acc[1][nt] = __builtin_amdgcn_mfma_f32_16x16x32_bf16(a1, bfr, acc[1][nt], 0, 0, 0);
            }
        }
    }

#pragma unroll
    for (int nt = 0; nt < 4; ++nt) {
        const int n = w * 64 + nt * 16 + c0;
        const float bb = b2[n];
#pragma unroll
        for (int r = 0; r < 4; ++r) {
            out[(tok0 + kg * 4 + r) * C_DIM + n]      = acc[0][nt][r] + bb;
            out[(tok0 + 16 + kg * 4 + r) * C_DIM + n] = acc[1][nt][r] + bb;
        }
    }
}

// ---------------------------------------------------------------------------
extern "C" void kernel_launch(void* const* d_in, const int* in_sizes, int n_in,
                              void* d_out, int out_size, void* d_ws, size_t ws_size,
                              hipStream_t stream) {
    const float* src   = (const float*)d_in[0];
    const float* pos   = (const float*)d_in[1];
    const float* refp  = (const float*)d_in[2];
    const float* Wv    = (const float*)d_in[3];
    const float* bv    = (const float*)d_in[4];
    const float* Wo    = (const float*)d_in[5];
    const float* bo    = (const float*)d_in[6];
    const float* Wa    = (const float*)d_in[7];
    const float* ba    = (const float*)d_in[8];
    const float* Wout  = (const float*)d_in[9];
    const float* bout  = (const float*)d_in[10];
    const float* gamma = (const float*)d_in[11];
    const float* beta  = (const float*)d_in[12];
    const float* W1    = (const float*)d_in[13];
    const float* b1    = (const float*)d_in[14];
    const float* W2    = (const float*)d_in[15];
    const float* b2    = (const float*)d_in[16];

    const size_t N256 = (size_t)NTOK * C_DIM;      // elements
    bf16*  srcb = (bf16*)d_ws;                     // NTOK*256 bf16
    bf16*  qb   = srcb + N256;                     // NTOK*256 bf16
    bf16*  val  = qb + N256;                       // NTOK*256 bf16
    float* loc  = (float*)(val + N256);            // NTOK*256 f32
    float* att  = loc + N256;                      // NTOK*128 f32
    bf16*  Wvt  = (bf16*)(att + (size_t)NTOK * 128);
    bf16*  Wqt  = Wvt + 256 * 256;                 // 384x256 (Wo^T | Wa^T)
    bf16*  Woutt= Wqt + 384 * 256;
    bf16*  W1t  = Woutt + 256 * 256;
    bf16*  W2t  = W1t + (size_t)FFN * C_DIM;
    bf16*  outb = srcb;                            // alias: srcb dead after value GEMM
    bf16*  xb   = qb;                              // alias: qb dead after qloc GEMM

    dim3 blk(256);
    k_prep<<<NCONV + 736, blk, 0, stream>>>(src, pos, srcb, qb,
                                            Wv, Wo, Wa, Wout, W1, W2,
                                            Wvt, Wqt, Woutt, W1t, W2t);
    k_vq  <<<2 * NTILE, blk, 0, stream>>>(srcb, qb, Wvt, bv, val,
                                          Wqt, bo, ba, refp, loc, att);
    k_samp<<<NTOK, blk, 0, stream>>>((const unsigned short*)val, loc, att, outb);
    k_post_mfma<<<NTILE, blk, 0, stream>>>(outb, Woutt, bout, src, gamma, beta, xb);
    k_ffn_mfma <<<NTILE, blk, 0, stream>>>(xb, W1t, b1, W2t, b2, (float*)d_out);
}